// Round 1
// baseline (2843.389 us; speedup 1.0000x reference)
//
#include <hip/hip_runtime.h>

typedef unsigned short u16;
typedef __bf16 bf16x8 __attribute__((ext_vector_type(8)));
typedef float f32x4 __attribute__((ext_vector_type(4)));

#define NN 8192
#define DD 256
#define BM 64
#define BK 64

// workspace layout (u16 elements)
#define XT_OFF   ((size_t)0)                    // X^T bf16 [256][8192]
#define XHI_OFF  ((size_t)2*1024*1024)          // X hi bf16 [8192][256]
#define XLO_OFF  ((size_t)4*1024*1024)          // X lo bf16 [8192][256]
#define MIN_OFF  ((size_t)6*1024*1024)          // msg_in  bf16 [4][8192][256]
#define MOUT_OFF ((size_t)14*1024*1024)         // msg_out bf16 [4][8192][256]
#define TT_OFF   ((size_t)22*1024*1024)         // 10 x W^T bf16 [256][256]

__device__ __forceinline__ u16 f2bf(float f) {
  union { float f; unsigned u; } a; a.f = f;
  unsigned u = a.u;
  unsigned r = u + 0x7fffu + ((u >> 16) & 1u);   // RNE
  return (u16)(r >> 16);
}
__device__ __forceinline__ float bf2f(u16 h) {
  union { unsigned u; float f; } a; a.u = ((unsigned)h) << 16;
  return a.f;
}

// ---- shared MFMA tile: C[64 x 256] += lA[64x64] * lB(256 cols)[.][64] ----
// lA: [m][k] bf16, row stride 128B, byte k-offset XOR-swizzled by ((m&7)<<4)
// lB: [n][k] bf16, same swizzle. Wave wv handles cols [wv*64, wv*64+64).
__device__ __forceinline__ void mma_tile(const u16* lA, const u16* lB,
                                         f32x4 (&acc)[4][4], int lane, int wv) {
#pragma unroll
  for (int kh = 0; kh < 2; ++kh) {
    const int kb = kh * 64 + ((lane >> 4) << 4);   // byte offset of this lane's 8 k's
    bf16x8 af[4], bv[4];
#pragma unroll
    for (int mi = 0; mi < 4; ++mi) {
      int row = mi * 16 + (lane & 15);
      af[mi] = *(const bf16x8*)((const char*)lA + row * 128 + (kb ^ ((row & 7) << 4)));
    }
#pragma unroll
    for (int ni = 0; ni < 4; ++ni) {
      int col = wv * 64 + ni * 16 + (lane & 15);
      bv[ni] = *(const bf16x8*)((const char*)lB + col * 128 + (kb ^ ((col & 7) << 4)));
    }
#pragma unroll
    for (int mi = 0; mi < 4; ++mi)
#pragma unroll
      for (int ni = 0; ni < 4; ++ni)
        acc[mi][ni] = __builtin_amdgcn_mfma_f32_16x16x32_bf16(af[mi], bv[ni], acc[mi][ni], 0, 0, 0);
  }
}

// ---- prep X: emit X_hi/X_lo (row major bf16) and XT (bf16 transpose) ----
__global__ __launch_bounds__(256)
void prep_x(const float* __restrict__ X, u16* __restrict__ XT,
            u16* __restrict__ Xhi, u16* __restrict__ Xlo) {
  __shared__ u16 tile[64][72];
  const int t = threadIdx.x;
  const int j0 = blockIdx.x * 64, d0 = blockIdx.y * 64;
#pragma unroll
  for (int it = 0; it < 4; ++it) {
    int j = it * 16 + (t >> 4);
    int dq = t & 15;
    float4 v = *(const float4*)&X[(size_t)(j0 + j) * DD + d0 + dq * 4];
    u16 h0 = f2bf(v.x), h1 = f2bf(v.y), h2 = f2bf(v.z), h3 = f2bf(v.w);
    uint2 hp; hp.x = h0 | ((unsigned)h1 << 16); hp.y = h2 | ((unsigned)h3 << 16);
    *(uint2*)&Xhi[(size_t)(j0 + j) * DD + d0 + dq * 4] = hp;
    u16 l0 = f2bf(v.x - bf2f(h0)), l1 = f2bf(v.y - bf2f(h1));
    u16 l2 = f2bf(v.z - bf2f(h2)), l3 = f2bf(v.w - bf2f(h3));
    uint2 lp; lp.x = l0 | ((unsigned)l1 << 16); lp.y = l2 | ((unsigned)l3 << 16);
    *(uint2*)&Xlo[(size_t)(j0 + j) * DD + d0 + dq * 4] = lp;
    *(uint2*)&tile[j][dq * 4] = hp;
  }
  __syncthreads();
#pragma unroll
  for (int it = 0; it < 2; ++it) {
    int d = t >> 2;
    int c = (t & 3) + it * 4;
    u16 o[8];
#pragma unroll
    for (int jj = 0; jj < 8; ++jj) o[jj] = tile[c * 8 + jj][d];
    uint4 pk;
    pk.x = o[0] | ((unsigned)o[1] << 16); pk.y = o[2] | ((unsigned)o[3] << 16);
    pk.z = o[4] | ((unsigned)o[5] << 16); pk.w = o[6] | ((unsigned)o[7] << 16);
    *(uint4*)&XT[(size_t)(d0 + d) * NN + j0 + c * 8] = pk;
  }
}

// ---- prep W: 10 transposed bf16 weight tables ----
// z=0: W_loop hi, z=1: W_loop lo, z=2..5: W_in[r], z=6..9: W_out[r]
__global__ __launch_bounds__(256)
void prep_w(const float* __restrict__ Wl, const float* __restrict__ Win,
            const float* __restrict__ Wout, u16* __restrict__ Tt) {
  int z = blockIdx.x;
  int t = threadIdx.x;               // n
  const float* src; int lo = 0;
  if (z == 0) src = Wl;
  else if (z == 1) { src = Wl; lo = 1; }
  else if (z < 6) src = Win + (size_t)(z - 2) * 65536;
  else src = Wout + (size_t)(z - 6) * 65536;
#pragma unroll
  for (int dk = 0; dk < 4; ++dk) {
    int k = blockIdx.y * 4 + dk;
    float v = src[(size_t)k * 256 + t];
    u16 h = f2bf(v);
    if (lo) h = f2bf(v - bf2f(h));
    Tt[(size_t)z * 65536 + (size_t)t * 256 + k] = h;  // [n][k]
  }
}

// ---- main pass: Msg[r] = rownorm( (TRANS? A_r^T : A_r) @ X ) as bf16 ----
template <int TRANS>
__global__ __launch_bounds__(256)
void spmm(const float* __restrict__ A, const u16* __restrict__ XT,
          u16* __restrict__ Msg) {
  __shared__ u16 lA[BM * BK];     // swizzled [64][64]
  __shared__ u16 lB[DD * BK];     // swizzled [256][64]
  __shared__ float red[BM];
  const int t = threadIdx.x;
  const int lane = t & 63, wv = t >> 6;
  const int r = blockIdx.y;
  const int i0 = blockIdx.x * BM;
  const float* __restrict__ Ar = A + (size_t)r * NN * NN;
  u16* __restrict__ Mout = Msg + (size_t)r * NN * DD;

  if (t < BM) red[t] = 0.f;

  f32x4 acc[4][4];
#pragma unroll
  for (int i = 0; i < 4; ++i)
#pragma unroll
    for (int j = 0; j < 4; ++j) acc[i][j] = (f32x4)0.f;

  float4 ra[4]; int4 rb[8];
  float rs0 = 0.f;
  float rs1[4] = {0.f, 0.f, 0.f, 0.f};

  auto LOAD = [&](int k0) {
    if constexpr (TRANS == 0) {
      const int m = t >> 2, q = t & 3;
      const float* p = Ar + (size_t)(i0 + m) * NN + k0 + q * 4;
#pragma unroll
      for (int dk = 0; dk < 4; ++dk)
        ra[dk] = *(const float4*)(p + dk * 16);
    } else {
      const int mq = t & 15, kq = t >> 4;
#pragma unroll
      for (int dk = 0; dk < 4; ++dk)
        ra[dk] = *(const float4*)(Ar + (size_t)(k0 + kq * 4 + dk) * NN + i0 + mq * 4);
    }
#pragma unroll
    for (int it = 0; it < 8; ++it) {
      int idx = it * 256 + t;
      int n = idx >> 3, c = idx & 7;
      rb[it] = *(const int4*)(XT + (size_t)n * NN + k0 + c * 8);
    }
  };

  auto WRITE = [&]() {
    if constexpr (TRANS == 0) {
      const int m = t >> 2, q = t & 3;
#pragma unroll
      for (int dk = 0; dk < 4; ++dk) {
        float4 v = ra[dk];
        rs0 += v.x + v.y + v.z + v.w;
        uint2 pk;
        pk.x = f2bf(v.x) | ((unsigned)f2bf(v.y) << 16);
        pk.y = f2bf(v.z) | ((unsigned)f2bf(v.w) << 16);
        int kb = (dk * 16 + q * 4) * 2;
        *(uint2*)((char*)lA + m * 128 + (kb ^ ((m & 7) << 4))) = pk;
      }
    } else {
      const int mq = t & 15, kq = t >> 4;
      const float* rf = reinterpret_cast<const float*>(&ra[0]);
#pragma unroll
      for (int dm = 0; dm < 4; ++dm) {
        int m = mq * 4 + dm;
        float e0 = rf[0 * 4 + dm], e1 = rf[1 * 4 + dm];
        float e2 = rf[2 * 4 + dm], e3 = rf[3 * 4 + dm];
        rs1[dm] += e0 + e1 + e2 + e3;
        uint2 pk;
        pk.x = f2bf(e0) | ((unsigned)f2bf(e1) << 16);
        pk.y = f2bf(e2) | ((unsigned)f2bf(e3) << 16);
        *(uint2*)((char*)lA + m * 128 + ((kq * 8) ^ ((m & 7) << 4))) = pk;
      }
    }
#pragma unroll
    for (int it = 0; it < 8; ++it) {
      int idx = it * 256 + t;
      int n = idx >> 3, c = idx & 7;
      *(int4*)((char*)lB + n * 128 + ((c * 16) ^ ((n & 7) << 4))) = rb[it];
    }
  };

  LOAD(0);
  for (int ks = 0; ks < NN / BK; ++ks) {
    __syncthreads();                 // all waves done reading previous tile
    WRITE();                         // implicit vmcnt wait on ra/rb
    __syncthreads();
    if (ks < NN / BK - 1) LOAD((ks + 1) * BK);   // in flight during MFMA
    mma_tile(lA, lB, acc, lane, wv);
  }

  // degree reduction
  if constexpr (TRANS == 0) {
    float v = rs0;
    v += __shfl_xor(v, 1);
    v += __shfl_xor(v, 2);
    if ((t & 3) == 0) red[t >> 2] = v;
  } else {
    const int mq = t & 15;
#pragma unroll
    for (int dm = 0; dm < 4; ++dm) {
      float v = rs1[dm];
      v += __shfl_xor(v, 16);
      v += __shfl_xor(v, 32);
      if (lane < 16) atomicAdd(&red[mq * 4 + dm], v);
    }
  }
  __syncthreads();
  if (t < BM) { float d = red[t]; red[t] = (d == 0.f) ? 1.f : 1.f / d; }
  __syncthreads();

  // normalize + store bf16
#pragma unroll
  for (int mi = 0; mi < 4; ++mi) {
#pragma unroll
    for (int rg = 0; rg < 4; ++rg) {
      int row = mi * 16 + ((lane >> 4) * 4) + rg;
      float inv = red[row];
#pragma unroll
      for (int ni = 0; ni < 4; ++ni) {
        int col = wv * 64 + ni * 16 + (lane & 15);
        float val = acc[mi][ni][rg] * inv;
        Mout[(size_t)(i0 + row) * DD + col] = f2bf(val);
      }
    }
  }
}

// ---- epilogue: out = relu( sum of 11 bf16 GEMM chunks ) ----
__global__ __launch_bounds__(256)
void final_gemm(const u16* __restrict__ ws, float* __restrict__ out) {
  __shared__ u16 lA[BM * BK];
  __shared__ u16 lB[DD * BK];
  const int t = threadIdx.x;
  const int lane = t & 63, wv = t >> 6;
  const int i0 = blockIdx.x * BM;

  f32x4 acc[4][4];
#pragma unroll
  for (int i = 0; i < 4; ++i)
#pragma unroll
    for (int j = 0; j < 4; ++j) acc[i][j] = (f32x4)0.f;

  for (int c = 0; c < 11; ++c) {
    const u16* S;
    if (c == 1) S = ws + XLO_OFF;
    else if (c < 3) S = ws + XHI_OFF;
    else if (c < 7) S = ws + MIN_OFF + (size_t)(c - 3) * NN * DD;
    else S = ws + MOUT_OFF + (size_t)(c - 7) * NN * DD;
    int z = (c < 2) ? 0 : (c == 2 ? 1 : c - 1);
    const u16* T = ws + TT_OFF + (size_t)z * 65536;

    for (int ksq = 0; ksq < 4; ++ksq) {
      int k0 = ksq * 64;
      int4 va[2], vb[8];
#pragma unroll
      for (int it = 0; it < 2; ++it) {
        int idx = it * 256 + t;
        int m = idx >> 3, ch = idx & 7;
        va[it] = *(const int4*)(S + (size_t)(i0 + m) * DD + k0 + ch * 8);
      }
#pragma unroll
      for (int it = 0; it < 8; ++it) {
        int idx = it * 256 + t;
        int n = idx >> 3, ch = idx & 7;
        vb[it] = *(const int4*)(T + (size_t)n * 256 + k0 + ch * 8);
      }
      __syncthreads();
#pragma unroll
      for (int it = 0; it < 2; ++it) {
        int idx = it * 256 + t;
        int m = idx >> 3, ch = idx & 7;
        *(int4*)((char*)lA + m * 128 + ((ch * 16) ^ ((m & 7) << 4))) = va[it];
      }
#pragma unroll
      for (int it = 0; it < 8; ++it) {
        int idx = it * 256 + t;
        int n = idx >> 3, ch = idx & 7;
        *(int4*)((char*)lB + n * 128 + ((ch * 16) ^ ((n & 7) << 4))) = vb[it];
      }
      __syncthreads();
      mma_tile(lA, lB, acc, lane, wv);
    }
  }

#pragma unroll
  for (int mi = 0; mi < 4; ++mi) {
#pragma unroll
    for (int rg = 0; rg < 4; ++rg) {
      int row = mi * 16 + ((lane >> 4) * 4) + rg;
#pragma unroll
      for (int ni = 0; ni < 4; ++ni) {
        int col = wv * 64 + ni * 16 + (lane & 15);
        float v = acc[mi][ni][rg];
        out[(size_t)(i0 + row) * DD + col] = v > 0.f ? v : 0.f;
      }
    }
  }
}

extern "C" void kernel_launch(void* const* d_in, const int* in_sizes, int n_in,
                              void* d_out, int out_size, void* d_ws, size_t ws_size,
                              hipStream_t stream) {
  const float* X    = (const float*)d_in[0];
  const float* A    = (const float*)d_in[1];
  const float* Wl   = (const float*)d_in[2];
  const float* Win  = (const float*)d_in[3];
  const float* Wout = (const float*)d_in[4];
  float* out = (float*)d_out;
  u16* ws = (u16*)d_ws;

  prep_x<<<dim3(NN / 64, DD / 64), 256, 0, stream>>>(X, ws + XT_OFF, ws + XHI_OFF, ws + XLO_OFF);
  prep_w<<<dim3(10, 64), 256, 0, stream>>>(Wl, Win, Wout, ws + TT_OFF);
  spmm<0><<<dim3(NN / BM, 4), 256, 0, stream>>>(A, ws + XT_OFF, ws + MIN_OFF);
  spmm<1><<<dim3(NN / BM, 4), 256, 0, stream>>>(A, ws + XT_OFF, ws + MOUT_OFF);
  final_gemm<<<dim3(NN / BM), 256, 0, stream>>>(ws, out);
}